// Round 4
// baseline (1158.652 us; speedup 1.0000x reference)
//
#include <hip/hip_runtime.h>

#define NT 4096
#define DD 1152
#define D3 3456
#define MLP_R 4304
#define MLP_P 4352
#define KP 640

typedef unsigned short u16;
typedef short v8s __attribute__((ext_vector_type(8)));
typedef float v4f __attribute__((ext_vector_type(4)));

__device__ __forceinline__ u16 f2b(float f) {
    unsigned int u = __builtin_bit_cast(unsigned int, f);
    u += 0x7fffu + ((u >> 16) & 1u);          // round-to-nearest-even
    return (u16)(u >> 16);
}
__device__ __forceinline__ float b2f(u16 s) {
    unsigned int u = ((unsigned int)s) << 16;
    return __builtin_bit_cast(float, u);
}

__device__ __forceinline__ void async16(const void* g, void* l) {
    __builtin_amdgcn_global_load_lds(
        (const __attribute__((address_space(1))) void*)g,
        (__attribute__((address_space(3))) void*)l, 16, 0, 0);
}

// ---------------------------------------------------------------------------
// GEMM: C[m][n] = sum_k A[m][k] * B[n][k]   (B transposed, K contiguous)
// MT x 128 block tile, BK=64. MT=128: 4 waves 2x2, wave=64x64. MT=64: 4 waves
// 1x4, wave=64x32. LDS tiles XOR-swizzled at 16B-chunk granularity (swizzle on
// the global source so global_load_lds lane-order is preserved). Staging
// addresses are pointer-inducted (+64 elems/iter) to kill per-iter 64-bit
// address VALU. Epilogue transposes acc through per-wave LDS scratch with NO
// barriers (intra-wave DS ops are in-order; K-loop's final barrier fences the
// union aliasing).
// EPI: 0 = bf16 out; 1 = bf16(acc+bias); 2 = bf16(gelu(acc+bias));
//      3 = f32 out[idx] = aux[idx] + acc + bias[n]
// ---------------------------------------------------------------------------
template<int EPI, int MT>
__global__ __launch_bounds__(256)
void gemm_bt(const u16* __restrict__ A, int lda,
             const u16* __restrict__ B, int ldb, int Kdim,
             const float* __restrict__ bias, const float* __restrict__ aux,
             float* __restrict__ outf, u16* __restrict__ outb, int ldc)
{
    constexpr int JT = (MT == 128) ? 4 : 2;   // 16-col j-tiles per wave
    constexpr int AR = MT * 8 / 256;          // A staging rounds (4 or 2)

    __shared__ union SM {
        struct { u16 a[MT * 64]; u16 b[128 * 64]; } st;
        float sc[4][64][17];
    } sm;

    const int tid  = threadIdx.x;
    const int m0   = blockIdx.y * MT;
    const int n0   = blockIdx.x * 128;
    const int lane = tid & 63;
    const int wave = tid >> 6;
    const int wm   = (MT == 128) ? (wave & 1) * 64 : 0;
    const int wn   = (MT == 128) ? (wave >> 1) * 64 : wave * 32;
    const int fr   = lane & 15;          // fragment row within 16
    const int kqh  = lane >> 4;          // k-quarter 0..3
    const int swz  = fr & 7;             // xor key (row&7 == fr&7 for all tiles)

    v4f acc[4][JT];
    const v4f vzero = {0.f, 0.f, 0.f, 0.f};
#pragma unroll
    for (int i = 0; i < 4; ++i)
#pragma unroll
        for (int j = 0; j < JT; ++j) acc[i][j] = vzero;

    u16* As = sm.st.a;
    u16* Bs = sm.st.b;

    // ---- staging pointers: computed once, inducted by += 64 per K-iter ----
    const u16* pa[AR];
    const u16* pb[4];
    u16* la[AR];
    u16* lb[4];
#pragma unroll
    for (int r = 0; r < AR; ++r) {
        int c = r * 256 + tid;
        int row = c >> 3;
        int kc = (c & 7) ^ (row & 7);
        pa[r] = A + (size_t)(m0 + row) * lda + kc * 8;
        la[r] = As + c * 8;
    }
#pragma unroll
    for (int r = 0; r < 4; ++r) {
        int c = r * 256 + tid;
        int row = c >> 3;
        int kc = (c & 7) ^ (row & 7);
        pb[r] = B + (size_t)(n0 + row) * ldb + kc * 8;
        lb[r] = Bs + c * 8;
    }

    // ---- LDS fragment read pointers (loop-invariant) ----
    const u16* fpa[2][4];
    const u16* fpb[2][4];
#pragma unroll
    for (int ks = 0; ks < 2; ++ks) {
        const int kp = ((ks * 4 + kqh) ^ swz) * 8;
#pragma unroll
        for (int i = 0; i < 4; ++i)
            fpa[ks][i] = As + (wm + i * 16 + fr) * 64 + kp;
#pragma unroll
        for (int j = 0; j < JT; ++j)
            fpb[ks][j] = Bs + (wn + j * 16 + fr) * 64 + kp;
    }

    for (int kt = 0; kt < Kdim; kt += 64) {
#pragma unroll
        for (int r = 0; r < AR; ++r) { async16(pa[r], la[r]); pa[r] += 64; }
#pragma unroll
        for (int r = 0; r < 4; ++r)  { async16(pb[r], lb[r]); pb[r] += 64; }
        __syncthreads();
#pragma unroll
        for (int ks = 0; ks < 2; ++ks) {
            v8s af[4], bf[JT];
#pragma unroll
            for (int i = 0; i < 4; ++i)
                af[i] = *(const v8s*)fpa[ks][i];
#pragma unroll
            for (int j = 0; j < JT; ++j)
                bf[j] = *(const v8s*)fpb[ks][j];
#pragma unroll
            for (int i = 0; i < 4; ++i)
#pragma unroll
                for (int j = 0; j < JT; ++j)
                    acc[i][j] = __builtin_amdgcn_mfma_f32_16x16x32_bf16(
                        af[i], bf[j], acc[i][j], 0, 0, 0);
        }
        __syncthreads();
    }

    // ---- epilogue via per-wave LDS transpose (no barriers needed) ----
    // acc C/D layout: col = lane&15, row = (lane>>4)*4 + reg
    const int cn = lane & 15;
    const int cm = (lane >> 4) * 4;
    float (*S)[17] = sm.sc[wave];
    const int gm = m0 + wm + lane;       // this thread's output row (store phase)
#pragma unroll
    for (int jp = 0; jp < JT; ++jp) {
#pragma unroll
        for (int i = 0; i < 4; ++i)
#pragma unroll
            for (int r = 0; r < 4; ++r)
                S[i * 16 + cm + r][cn] = acc[i][jp][r];
        __builtin_amdgcn_wave_barrier();   // pin ordering; DS ops in-order per wave
        const int gn0 = n0 + wn + jp * 16;
        float v[16];
#pragma unroll
        for (int c = 0; c < 16; ++c) v[c] = S[lane][c];
        __builtin_amdgcn_wave_barrier();
        if constexpr (EPI <= 2) {
            union { u16 us[16]; uint4 q[2]; } o;
#pragma unroll
            for (int c = 0; c < 16; ++c) {
                float t = v[c];
                if constexpr (EPI >= 1) t += bias[gn0 + c];
                if constexpr (EPI == 2)
                    t = t * 0.5f * (1.0f + erff(t * 0.70710678118654752f));
                o.us[c] = f2b(t);
            }
            uint4* dst = (uint4*)(outb + (size_t)gm * ldc + gn0);
            dst[0] = o.q[0];
            dst[1] = o.q[1];
        } else {
            float* dst = outf + (size_t)gm * ldc + gn0;
            const float* ax = aux + (size_t)gm * ldc + gn0;
#pragma unroll
            for (int c = 0; c < 4; ++c) {
                float4 a4 = ((const float4*)ax)[c];
                float4 r4;
                r4.x = a4.x + v[4 * c + 0] + bias[gn0 + 4 * c + 0];
                r4.y = a4.y + v[4 * c + 1] + bias[gn0 + 4 * c + 1];
                r4.z = a4.z + v[4 * c + 2] + bias[gn0 + 4 * c + 2];
                r4.w = a4.w + v[4 * c + 3] + bias[gn0 + 4 * c + 3];
                ((float4*)dst)[c] = r4;
            }
        }
    }
}

// ---------------------------------------------------------------------------
// LayerNorm over D=1152. 384 threads, 3 elems each. OUTF=1 -> f32, else bf16.
// ---------------------------------------------------------------------------
template<int OUTF>
__global__ __launch_bounds__(384)
void ln_kernel(const float* __restrict__ x, const float* __restrict__ w,
               const float* __restrict__ b, void* __restrict__ out)
{
    const int n = blockIdx.x;
    const int t = threadIdx.x;
    const float* row = x + (size_t)n * DD;
    float v0 = row[t], v1 = row[t + 384], v2 = row[t + 768];
    float s  = v0 + v1 + v2;
    float ss = v0 * v0 + v1 * v1 + v2 * v2;
#pragma unroll
    for (int o = 32; o > 0; o >>= 1) {
        s  += __shfl_down(s, o);
        ss += __shfl_down(ss, o);
    }
    __shared__ float ps[6], pss[6], mh[2];
    if ((t & 63) == 0) { ps[t >> 6] = s; pss[t >> 6] = ss; }
    __syncthreads();
    if (t == 0) {
        float S = 0.f, SS = 0.f;
        for (int i = 0; i < 6; ++i) { S += ps[i]; SS += pss[i]; }
        float m = S / (float)DD;
        float var = SS / (float)DD - m * m;
        mh[0] = m;
        mh[1] = rsqrtf(var + 1e-6f);
    }
    __syncthreads();
    const float m = mh[0], rs = mh[1];
#pragma unroll
    for (int j = 0; j < 3; ++j) {
        int c = t + j * 384;
        float y = (row[c] - m) * rs * w[c] + b[c];
        if constexpr (OUTF) ((float*)out)[(size_t)n * DD + c] = y;
        else                ((u16*)out)[(size_t)n * DD + c]   = f2b(y);
    }
}

// ---------------------------------------------------------------------------
// Softmax over rows of bf16 scores [NT x NT], in place, with scale.
// ---------------------------------------------------------------------------
__global__ __launch_bounds__(256)
void softmax_kernel(u16* __restrict__ s)
{
    const float SC = 0.029462782549439484f;  // 1/sqrt(1152)
    const int row = blockIdx.x;
    const int t = threadIdx.x;
    u16* p = s + (size_t)row * NT + t * 16;
    uint4 u0 = *(const uint4*)p;
    uint4 u1 = *(const uint4*)(p + 8);
    float v[16];
    unsigned int w[8] = {u0.x, u0.y, u0.z, u0.w, u1.x, u1.y, u1.z, u1.w};
#pragma unroll
    for (int i = 0; i < 8; ++i) {
        v[2 * i]     = b2f((u16)(w[i] & 0xffffu)) * SC;
        v[2 * i + 1] = b2f((u16)(w[i] >> 16)) * SC;
    }
    float mx = -1e30f;
#pragma unroll
    for (int i = 0; i < 16; ++i) mx = fmaxf(mx, v[i]);
#pragma unroll
    for (int o = 32; o > 0; o >>= 1) mx = fmaxf(mx, __shfl_down(mx, o));
    __shared__ float red[4];
    __shared__ float bc;
    if ((t & 63) == 0) red[t >> 6] = mx;
    __syncthreads();
    if (t == 0) bc = fmaxf(fmaxf(red[0], red[1]), fmaxf(red[2], red[3]));
    __syncthreads();
    const float M = bc;
    float sum = 0.f;
#pragma unroll
    for (int i = 0; i < 16; ++i) { v[i] = __expf(v[i] - M); sum += v[i]; }
#pragma unroll
    for (int o = 32; o > 0; o >>= 1) sum += __shfl_down(sum, o);
    __syncthreads();
    if ((t & 63) == 0) red[t >> 6] = sum;
    __syncthreads();
    if (t == 0) bc = red[0] + red[1] + red[2] + red[3];
    __syncthreads();
    const float inv = 1.0f / bc;
    union { u16 us[8]; uint4 u4; } o0, o1;
#pragma unroll
    for (int i = 0; i < 8; ++i) o0.us[i] = f2b(v[i] * inv);
#pragma unroll
    for (int i = 0; i < 8; ++i) o1.us[i] = f2b(v[8 + i] * inv);
    *(uint4*)p = o0.u4;
    *(uint4*)(p + 8) = o1.u4;
}

// ---------------------------------------------------------------------------
// pos [DD][NT] -> pos_t [NT][DD]  (fp32 tiled transpose)
// ---------------------------------------------------------------------------
__global__ __launch_bounds__(256)
void transpose_pos(const float* __restrict__ src, float* __restrict__ dst)
{
    __shared__ float tile[32][33];
    const int tx = threadIdx.x, ty = threadIdx.y;
    const int c0 = blockIdx.x * 32;
    const int r0 = blockIdx.y * 32;
#pragma unroll
    for (int i = 0; i < 4; ++i)
        tile[ty + 8 * i][tx] = src[(size_t)(r0 + ty + 8 * i) * NT + c0 + tx];
    __syncthreads();
#pragma unroll
    for (int i = 0; i < 4; ++i)
        dst[(size_t)(c0 + ty + 8 * i) * DD + r0 + tx] = tile[tx][ty + 8 * i];
}

// ---------------------------------------------------------------------------
// V section of qkv [NT][3456] (cols 2304..3455) -> vt [DD][NT]  (bf16)
// ---------------------------------------------------------------------------
__global__ __launch_bounds__(256)
void transpose_v(const u16* __restrict__ qkv, u16* __restrict__ vt)
{
    __shared__ u16 tile[32][33];
    const int tx = threadIdx.x, ty = threadIdx.y;
    const int d0 = blockIdx.x * 32;
    const int n0 = blockIdx.y * 32;
#pragma unroll
    for (int i = 0; i < 4; ++i)
        tile[ty + 8 * i][tx] = qkv[(size_t)(n0 + ty + 8 * i) * D3 + 2304 + d0 + tx];
    __syncthreads();
#pragma unroll
    for (int i = 0; i < 4; ++i)
        vt[(size_t)(d0 + ty + 8 * i) * NT + n0 + tx] = tile[tx][ty + 8 * i];
}

// ---------------------------------------------------------------------------
// im2col: img [3][896][896] -> a [NT][KP] bf16 (k = cin*196+py*14+px, pad->0)
// ---------------------------------------------------------------------------
__global__ __launch_bounds__(256)
void im2col_kernel(const float* __restrict__ img, u16* __restrict__ a)
{
    const int k = blockIdx.x * 256 + threadIdx.x;
    const int n = blockIdx.y;
    if (k >= KP) return;
    float v = 0.f;
    if (k < 588) {
        int cin = k / 196;
        int rr = k - cin * 196;
        int py = rr / 14;
        int px = rr - py * 14;
        int gy = (n >> 6) * 14 + py;
        int gx = (n & 63) * 14 + px;
        v = img[(size_t)cin * 896 * 896 + (size_t)gy * 896 + gx];
    }
    a[(size_t)n * KP + k] = f2b(v);
}

// ---------------------------------------------------------------------------
// fp32 -> bf16 convert with column padding (c >= Cin -> 0)
// ---------------------------------------------------------------------------
__global__ __launch_bounds__(256)
void pad_cvt(u16* __restrict__ dst, const float* __restrict__ src, int Cin, int Cout)
{
    const int c = blockIdx.x * 256 + threadIdx.x;
    const int r = blockIdx.y;
    if (c >= Cout) return;
    float v = (c < Cin) ? src[(size_t)r * Cin + c] : 0.f;
    dst[(size_t)r * Cout + c] = f2b(v);
}

__global__ __launch_bounds__(256)
void pad_f32(float* __restrict__ dst, const float* __restrict__ src, int Cin, int Cout)
{
    const int c = blockIdx.x * 256 + threadIdx.x;
    const int r = blockIdx.y;
    if (c >= Cout) return;
    dst[(size_t)r * Cout + c] = (c < Cin) ? src[(size_t)r * Cin + c] : 0.f;
}

// ---------------------------------------------------------------------------
// Workspace layout (bytes)
// ---------------------------------------------------------------------------
constexpr size_t OFF_X      = 0;                                  // f32 [NT][DD]
constexpr size_t OFF_HBF    = OFF_X      + (size_t)NT * DD * 4;   // bf16 [NT][DD]
constexpr size_t OFF_TMP    = OFF_HBF    + (size_t)NT * DD * 2;   // bf16 max(NT*MLP_P, NT*NT)
constexpr size_t OFF_QKV    = OFF_TMP    + (size_t)NT * MLP_P * 2;// bf16 [NT][D3]
constexpr size_t OFF_VT     = OFF_QKV    + (size_t)NT * D3 * 2;   // bf16 [DD][NT]
constexpr size_t OFF_IM     = OFF_VT     + (size_t)DD * NT * 2;   // bf16 [NT][KP]
constexpr size_t OFF_POST   = OFF_IM     + (size_t)NT * KP * 2;   // f32 [NT][DD]
constexpr size_t OFF_WQKV   = OFF_POST   + (size_t)NT * DD * 4;   // bf16 [2][D3][DD]
constexpr size_t OFF_WPROJ  = OFF_WQKV   + (size_t)2 * D3 * DD * 2;
constexpr size_t OFF_WFC1   = OFF_WPROJ  + (size_t)2 * DD * DD * 2;   // [2][MLP_P][DD]
constexpr size_t OFF_WFC2   = OFF_WFC1   + (size_t)2 * MLP_P * DD * 2;// [2][DD][MLP_P]
constexpr size_t OFF_WPATCH = OFF_WFC2   + (size_t)2 * DD * MLP_P * 2;// [DD][KP]
constexpr size_t OFF_FC1B   = OFF_WPATCH + (size_t)DD * KP * 2;       // f32 [2][MLP_P]

extern "C" void kernel_launch(void* const* d_in, const int* in_sizes, int n_in,
                              void* d_out, int out_size, void* d_ws, size_t ws_size,
                              hipStream_t stream)
{
    const float* img     = (const float*)d_in[0];
    const float* patch_w = (const float*)d_in[1];
    const float* patch_b = (const float*)d_in[2];
    const float* pos     = (const float*)d_in[3];
    const float* ln1_w   = (const float*)d_in[4];
    const float* ln1_b   = (const float*)d_in[5];
    const float* qkv_w   = (const float*)d_in[6];
    const float* qkv_b   = (const float*)d_in[7];
    const float* proj_w  = (const float*)d_in[8];
    const float* proj_b  = (const float*)d_in[9];
    const float* ln2_w   = (const float*)d_in[10];
    const float* ln2_b   = (const float*)d_in[11];
    const float* fc1_w   = (const float*)d_in[12];
    const float* fc1_b   = (const float*)d_in[13];
    const float* fc2_w   = (const float*)d_in[14];
    const float* fc2_b   = (const float*)d_in[15];
    const float* post_w  = (const float*)d_in[16];
    const float* post_b  = (const float*)d_in[17];

    char* ws = (char*)d_ws;
    float* x      = (float*)(ws + OFF_X);
    u16*  h_bf    = (u16*)(ws + OFF_HBF);
    u16*  tmp_bf  = (u16*)(ws + OFF_TMP);
    u16*  qkv_bf  = (u16*)(ws + OFF_QKV);
    u16*  vt      = (u16*)(ws + OFF_VT);
    u16*  a_im    = (u16*)(ws + OFF_IM);
    float* pos_t  = (float*)(ws + OFF_POST);
    u16*  w_qkv   = (u16*)(ws + OFF_WQKV);
    u16*  w_proj  = (u16*)(ws + OFF_WPROJ);
    u16*  w_fc1   = (u16*)(ws + OFF_WFC1);
    u16*  w_fc2   = (u16*)(ws + OFF_WFC2);
    u16*  w_pat   = (u16*)(ws + OFF_WPATCH);
    float* fc1b_p = (float*)(ws + OFF_FC1B);

    // ---- weight/bias conversion (inputs re-poisoned every call) ----
    pad_cvt<<<dim3(5, 2 * D3), 256, 0, stream>>>(w_qkv, qkv_w, DD, DD);
    pad_cvt<<<dim3(5, 2 * DD), 256, 0, stream>>>(w_proj, proj_w, DD, DD);
    pad_cvt<<<dim3(19584, 2), 256, 0, stream>>>(w_fc1, fc1_w, MLP_R * DD, MLP_P * DD);
    pad_cvt<<<dim3(17, 2 * DD), 256, 0, stream>>>(w_fc2, fc2_w, MLP_R, MLP_P);
    pad_cvt<<<dim3(3, DD), 256, 0, stream>>>(w_pat, patch_w, 588, KP);
    pad_f32<<<dim3(17, 2), 256, 0, stream>>>(fc1b_p, fc1_b, MLP_R, MLP_P);
    transpose_pos<<<dim3(128, 36), dim3(32, 8), 0, stream>>>(pos, pos_t);
    im2col_kernel<<<dim3(3, NT), 256, 0, stream>>>(img, a_im);

    // ---- patch embed: x = im2col * patch_w^T + patch_b + pos_t ----
    gemm_bt<3, 64><<<dim3(9, 64), 256, 0, stream>>>(a_im, KP, w_pat, KP, KP,
                                                    patch_b, pos_t, x, nullptr, DD);

    for (int l = 0; l < 2; ++l) {
        // LN1 -> bf16
        ln_kernel<0><<<NT, 384, 0, stream>>>(x, ln1_w + l * DD, ln1_b + l * DD, h_bf);
        // QKV = h * Wqkv^T + b
        gemm_bt<1, 128><<<dim3(27, 32), 256, 0, stream>>>(
            h_bf, DD, w_qkv + (size_t)l * D3 * DD, DD, DD,
            qkv_b + (size_t)l * D3, nullptr, nullptr, qkv_bf, D3);
        // scores = Q K^T (bf16 out, scaled inside softmax)
        gemm_bt<0, 128><<<dim3(32, 32), 256, 0, stream>>>(
            qkv_bf, D3, qkv_bf + DD, D3, DD,
            nullptr, nullptr, nullptr, tmp_bf, NT);
        // V^T for the PV GEMM
        transpose_v<<<dim3(36, 128), dim3(32, 8), 0, stream>>>(qkv_bf, vt);
        // softmax rows (in place)
        softmax_kernel<<<NT, 256, 0, stream>>>(tmp_bf);
        // attn_out = P * V   (B = V^T)
        gemm_bt<0, 64><<<dim3(9, 64), 256, 0, stream>>>(
            tmp_bf, NT, vt, NT, NT, nullptr, nullptr, nullptr, h_bf, DD);
        // x += attn_out * Wproj^T + b
        gemm_bt<3, 64><<<dim3(9, 64), 256, 0, stream>>>(
            h_bf, DD, w_proj + (size_t)l * DD * DD, DD, DD,
            proj_b + (size_t)l * DD, x, x, nullptr, DD);
        // LN2 -> bf16
        ln_kernel<0><<<NT, 384, 0, stream>>>(x, ln2_w + l * DD, ln2_b + l * DD, h_bf);
        // h2 = gelu(h * Wfc1^T + b)   (MLP padded 4304 -> 4352, pad cols = 0)
        gemm_bt<2, 128><<<dim3(34, 32), 256, 0, stream>>>(
            h_bf, DD, w_fc1 + (size_t)l * MLP_P * DD, DD, DD,
            fc1b_p + (size_t)l * MLP_P, nullptr, nullptr, tmp_bf, MLP_P);
        // x += h2 * Wfc2^T + b
        gemm_bt<3, 64><<<dim3(9, 64), 256, 0, stream>>>(
            tmp_bf, MLP_P, w_fc2 + (size_t)l * DD * MLP_P, MLP_P, MLP_P,
            fc2_b + (size_t)l * DD, x, x, nullptr, DD);
    }
    // final LN -> f32 d_out
    ln_kernel<1><<<NT, 384, 0, stream>>>(x, post_w, post_b, d_out);
}

// Round 5
// 1003.795 us; speedup vs baseline: 1.1543x; 1.1543x over previous
//
#include <hip/hip_runtime.h>

#define NT 4096
#define DD 1152
#define D3 3456
#define MLP_R 4304
#define MLP_P 4352
#define KP 640

typedef unsigned short u16;
typedef short v8s __attribute__((ext_vector_type(8)));
typedef float v4f __attribute__((ext_vector_type(4)));

__device__ __forceinline__ u16 f2b(float f) {
    unsigned int u = __builtin_bit_cast(unsigned int, f);
    u += 0x7fffu + ((u >> 16) & 1u);          // round-to-nearest-even
    return (u16)(u >> 16);
}
__device__ __forceinline__ float b2f(u16 s) {
    unsigned int u = ((unsigned int)s) << 16;
    return __builtin_bit_cast(float, u);
}

__device__ __forceinline__ void async16(const void* g, void* l) {
    __builtin_amdgcn_global_load_lds(
        (const __attribute__((address_space(1))) void*)g,
        (__attribute__((address_space(3))) void*)l, 16, 0, 0);
}

// ---------------------------------------------------------------------------
// GEMM: C[m][n] = sum_k A[m][k] * B[n][k]   (B transposed, K contiguous)
// Round-3 core (proven): MT x 128 tile, BK=64, XOR-swizzled LDS (16B chunks,
// swizzle on global source so global_load_lds lane-order is preserved),
// epilogue via LDS transpose for 16B-vectorized stores.
// EPI: 0 = bf16 out; 1 = bf16(acc+bias), + transposed V store when vt!=null;
//      2 = bf16(gelu(acc+bias)); 3 = f32 out = aux + acc + bias;
//      4 = f32 out = acc + bias[n] + pos[n][m]  (aux = pos, [D][NT] layout)
// ---------------------------------------------------------------------------
template<int EPI, int MT>
__global__ __launch_bounds__(256)
void gemm_bt(const u16* __restrict__ A, int lda,
             const u16* __restrict__ B, int ldb, int Kdim,
             const float* __restrict__ bias, const float* __restrict__ aux,
             float* __restrict__ outf, u16* __restrict__ outb, int ldc,
             u16* __restrict__ vt)
{
    constexpr int JT = (MT == 128) ? 4 : 2;   // 16-col j-tiles per wave
    constexpr int AR = MT * 8 / 256;          // A staging rounds (4 or 2)

    __shared__ union SM {
        struct { u16 a[MT * 64]; u16 b[128 * 64]; } st;
        float sc[4][64][17];
    } sm;

    const int tid  = threadIdx.x;
    const int m0   = blockIdx.y * MT;
    const int n0   = blockIdx.x * 128;
    const int lane = tid & 63;
    const int wave = tid >> 6;
    const int wm   = (MT == 128) ? (wave & 1) * 64 : 0;
    const int wn   = (MT == 128) ? (wave >> 1) * 64 : wave * 32;
    const int fr   = lane & 15;          // fragment row within 16
    const int kqh  = lane >> 4;          // k-quarter 0..3
    const int swz  = fr & 7;             // xor key (row&7 == fr&7 for all tiles)

    v4f acc[4][JT];
    const v4f vzero = {0.f, 0.f, 0.f, 0.f};
#pragma unroll
    for (int i = 0; i < 4; ++i)
#pragma unroll
        for (int j = 0; j < JT; ++j) acc[i][j] = vzero;

    u16* As = sm.st.a;
    u16* Bs = sm.st.b;

    for (int kt = 0; kt < Kdim; kt += 64) {
#pragma unroll
        for (int r = 0; r < AR; ++r) {
            int c = r * 256 + tid;
            int row = c >> 3;
            int kc = (c & 7) ^ (row & 7);
            async16(A + (size_t)(m0 + row) * lda + kt + kc * 8, As + c * 8);
        }
#pragma unroll
        for (int r = 0; r < 4; ++r) {
            int c = r * 256 + tid;
            int row = c >> 3;
            int kc = (c & 7) ^ (row & 7);
            async16(B + (size_t)(n0 + row) * ldb + kt + kc * 8, Bs + c * 8);
        }
        __syncthreads();
#pragma unroll
        for (int ks = 0; ks < 2; ++ks) {
            const int kq = ks * 4 + kqh;
            const int kp = (kq ^ swz) * 8;
            v8s af[4], bf[JT];
#pragma unroll
            for (int i = 0; i < 4; ++i)
                af[i] = *(const v8s*)(As + (wm + i * 16 + fr) * 64 + kp);
#pragma unroll
            for (int j = 0; j < JT; ++j)
                bf[j] = *(const v8s*)(Bs + (wn + j * 16 + fr) * 64 + kp);
#pragma unroll
            for (int i = 0; i < 4; ++i)
#pragma unroll
                for (int j = 0; j < JT; ++j)
                    acc[i][j] = __builtin_amdgcn_mfma_f32_16x16x32_bf16(
                        af[i], bf[j], acc[i][j], 0, 0, 0);
        }
        __syncthreads();
    }

    // ---- epilogue via LDS transpose ----
    // acc C/D layout: col = lane&15, row = (lane>>4)*4 + reg
    const int cn = lane & 15;
    const int cm = (lane >> 4) * 4;
    float (*S)[17] = sm.sc[wave];
    const int gm = m0 + wm + lane;       // this thread's output row (store phase)
#pragma unroll
    for (int jp = 0; jp < JT; ++jp) {
        __syncthreads();
#pragma unroll
        for (int i = 0; i < 4; ++i)
#pragma unroll
            for (int r = 0; r < 4; ++r)
                S[i * 16 + cm + r][cn] = acc[i][jp][r];
        __syncthreads();
        const int gn0 = n0 + wn + jp * 16;
        float v[16];
#pragma unroll
        for (int c = 0; c < 16; ++c) v[c] = S[lane][c];
        if constexpr (EPI <= 2) {
            union { u16 us[16]; uint4 q[2]; } o;
#pragma unroll
            for (int c = 0; c < 16; ++c) {
                float t = v[c];
                if constexpr (EPI >= 1) t += bias[gn0 + c];
                if constexpr (EPI == 2) {
                    // tanh-form gelu: t * sigmoid(2u), u = 0.79788t(1+0.044715t^2)
                    float u = t * (0.7978845608028654f + 0.03567740814183026f * t * t);
                    t = t / (1.0f + __expf(-2.0f * u));
                }
                o.us[c] = f2b(t);
            }
            uint4* dst = (uint4*)(outb + (size_t)gm * ldc + gn0);
            dst[0] = o.q[0];
            dst[1] = o.q[1];
            if constexpr (EPI == 1) {
                // fused V-transpose: V section of qkv -> vt [DD][NT]
                if (vt != nullptr && gn0 >= 2304) {
#pragma unroll
                    for (int c = 0; c < 16; ++c)
                        vt[(size_t)(gn0 + c - 2304) * NT + gm] = o.us[c];
                }
            }
        } else if constexpr (EPI == 3) {
            float* dst = outf + (size_t)gm * ldc + gn0;
            const float* ax = aux + (size_t)gm * ldc + gn0;
#pragma unroll
            for (int c = 0; c < 4; ++c) {
                float4 a4 = ((const float4*)ax)[c];
                float4 r4;
                r4.x = a4.x + v[4 * c + 0] + bias[gn0 + 4 * c + 0];
                r4.y = a4.y + v[4 * c + 1] + bias[gn0 + 4 * c + 1];
                r4.z = a4.z + v[4 * c + 2] + bias[gn0 + 4 * c + 2];
                r4.w = a4.w + v[4 * c + 3] + bias[gn0 + 4 * c + 3];
                ((float4*)dst)[c] = r4;
            }
        } else {
            // EPI 4: patch embed. aux = pos in [D][NT] layout, read transposed
            // (coalesced across lanes since gm is lane-consecutive).
            float* dst = outf + (size_t)gm * ldc + gn0;
#pragma unroll
            for (int c = 0; c < 4; ++c) {
                float4 r4;
                r4.x = v[4 * c + 0] + bias[gn0 + 4 * c + 0] + aux[(size_t)(gn0 + 4 * c + 0) * NT + gm];
                r4.y = v[4 * c + 1] + bias[gn0 + 4 * c + 1] + aux[(size_t)(gn0 + 4 * c + 1) * NT + gm];
                r4.z = v[4 * c + 2] + bias[gn0 + 4 * c + 2] + aux[(size_t)(gn0 + 4 * c + 2) * NT + gm];
                r4.w = v[4 * c + 3] + bias[gn0 + 4 * c + 3] + aux[(size_t)(gn0 + 4 * c + 3) * NT + gm];
                ((float4*)dst)[c] = r4;
            }
        }
    }
}

// ---------------------------------------------------------------------------
// LayerNorm over D=1152. 384 threads, 3 elems each. OUTF=1 -> f32, else bf16.
// ---------------------------------------------------------------------------
template<int OUTF>
__global__ __launch_bounds__(384)
void ln_kernel(const float* __restrict__ x, const float* __restrict__ w,
               const float* __restrict__ b, void* __restrict__ out)
{
    const int n = blockIdx.x;
    const int t = threadIdx.x;
    const float* row = x + (size_t)n * DD;
    float v0 = row[t], v1 = row[t + 384], v2 = row[t + 768];
    float s  = v0 + v1 + v2;
    float ss = v0 * v0 + v1 * v1 + v2 * v2;
#pragma unroll
    for (int o = 32; o > 0; o >>= 1) {
        s  += __shfl_down(s, o);
        ss += __shfl_down(ss, o);
    }
    __shared__ float ps[6], pss[6], mh[2];
    if ((t & 63) == 0) { ps[t >> 6] = s; pss[t >> 6] = ss; }
    __syncthreads();
    if (t == 0) {
        float S = 0.f, SS = 0.f;
        for (int i = 0; i < 6; ++i) { S += ps[i]; SS += pss[i]; }
        float m = S / (float)DD;
        float var = SS / (float)DD - m * m;
        mh[0] = m;
        mh[1] = rsqrtf(var + 1e-6f);
    }
    __syncthreads();
    const float m = mh[0], rs = mh[1];
#pragma unroll
    for (int j = 0; j < 3; ++j) {
        int c = t + j * 384;
        float y = (row[c] - m) * rs * w[c] + b[c];
        if constexpr (OUTF) ((float*)out)[(size_t)n * DD + c] = y;
        else                ((u16*)out)[(size_t)n * DD + c]   = f2b(y);
    }
}

// ---------------------------------------------------------------------------
// Softmax over rows of bf16 scores [NT x NT], in place, with scale.
// ---------------------------------------------------------------------------
__global__ __launch_bounds__(256)
void softmax_kernel(u16* __restrict__ s)
{
    const float SC = 0.029462782549439484f;  // 1/sqrt(1152)
    const int row = blockIdx.x;
    const int t = threadIdx.x;
    u16* p = s + (size_t)row * NT + t * 16;
    uint4 u0 = *(const uint4*)p;
    uint4 u1 = *(const uint4*)(p + 8);
    float v[16];
    unsigned int w[8] = {u0.x, u0.y, u0.z, u0.w, u1.x, u1.y, u1.z, u1.w};
#pragma unroll
    for (int i = 0; i < 8; ++i) {
        v[2 * i]     = b2f((u16)(w[i] & 0xffffu)) * SC;
        v[2 * i + 1] = b2f((u16)(w[i] >> 16)) * SC;
    }
    float mx = -1e30f;
#pragma unroll
    for (int i = 0; i < 16; ++i) mx = fmaxf(mx, v[i]);
#pragma unroll
    for (int o = 32; o > 0; o >>= 1) mx = fmaxf(mx, __shfl_down(mx, o));
    __shared__ float red[4];
    __shared__ float bc;
    if ((t & 63) == 0) red[t >> 6] = mx;
    __syncthreads();
    if (t == 0) bc = fmaxf(fmaxf(red[0], red[1]), fmaxf(red[2], red[3]));
    __syncthreads();
    const float M = bc;
    float sum = 0.f;
#pragma unroll
    for (int i = 0; i < 16; ++i) { v[i] = __expf(v[i] - M); sum += v[i]; }
#pragma unroll
    for (int o = 32; o > 0; o >>= 1) sum += __shfl_down(sum, o);
    __syncthreads();
    if ((t & 63) == 0) red[t >> 6] = sum;
    __syncthreads();
    if (t == 0) bc = red[0] + red[1] + red[2] + red[3];
    __syncthreads();
    const float inv = 1.0f / bc;
    union { u16 us[8]; uint4 u4; } o0, o1;
#pragma unroll
    for (int i = 0; i < 8; ++i) o0.us[i] = f2b(v[i] * inv);
#pragma unroll
    for (int i = 0; i < 8; ++i) o1.us[i] = f2b(v[8 + i] * inv);
    *(uint4*)p = o0.u4;
    *(uint4*)(p + 8) = o1.u4;
}

// ---------------------------------------------------------------------------
// im2col: img [3][896][896] -> a [NT][KP] bf16 (k = cin*196+py*14+px, pad->0)
// ---------------------------------------------------------------------------
__global__ __launch_bounds__(256)
void im2col_kernel(const float* __restrict__ img, u16* __restrict__ a)
{
    const int k = blockIdx.x * 256 + threadIdx.x;
    const int n = blockIdx.y;
    if (k >= KP) return;
    float v = 0.f;
    if (k < 588) {
        int cin = k / 196;
        int rr = k - cin * 196;
        int py = rr / 14;
        int px = rr - py * 14;
        int gy = (n >> 6) * 14 + py;
        int gx = (n & 63) * 14 + px;
        v = img[(size_t)cin * 896 * 896 + (size_t)gy * 896 + gx];
    }
    a[(size_t)n * KP + k] = f2b(v);
}

// ---------------------------------------------------------------------------
// One fused, float4-vectorized weight conversion/pad kernel.
// Segments (in vec4 units of the DESTINATION):
//   s0 qkv  [2][3456][1152] direct
//   s1 proj [2][1152][1152] direct
//   s2 fc1  [2][4352][1152] row-pad (src rows 4304)
//   s3 fc2  [2][1152][4352] col-pad (src cols 4304)
//   s4 pat  [1152][640]     col-pad (src cols 588)
//   s5 fc1b [2][4352] f32   col-pad
// ---------------------------------------------------------------------------
constexpr int CV_S0 = 2 * D3 * DD / 4;                 // 1990656
constexpr int CV_S1 = CV_S0 + 2 * DD * DD / 4;         // +663552
constexpr int CV_S2 = CV_S1 + 2 * MLP_P * DD / 4;      // +2506752
constexpr int CV_S3 = CV_S2 + 2 * DD * MLP_P / 4;      // +2506752
constexpr int CV_S4 = CV_S3 + DD * KP / 4;             // +184320
constexpr int CV_S5 = CV_S4 + 2 * MLP_P / 4;           // +2176
constexpr int CV_BLOCKS = (CV_S5 + 255) / 256;

__device__ __forceinline__ void store_bf4(u16* p, float4 f) {
    union { u16 s[4]; uint2 d; } o;
    o.s[0] = f2b(f.x); o.s[1] = f2b(f.y); o.s[2] = f2b(f.z); o.s[3] = f2b(f.w);
    *(uint2*)p = o.d;
}

__global__ __launch_bounds__(256)
void convert_all(const float* __restrict__ qkv_w, const float* __restrict__ proj_w,
                 const float* __restrict__ fc1_w, const float* __restrict__ fc2_w,
                 const float* __restrict__ patch_w, const float* __restrict__ fc1_b,
                 u16* __restrict__ w_qkv, u16* __restrict__ w_proj,
                 u16* __restrict__ w_fc1, u16* __restrict__ w_fc2,
                 u16* __restrict__ w_pat, float* __restrict__ fc1b_p)
{
    int v = blockIdx.x * 256 + threadIdx.x;
    if (v >= CV_S5) return;
    const float4 z4 = {0.f, 0.f, 0.f, 0.f};
    if (v < CV_S0) {
        store_bf4(w_qkv + (size_t)v * 4, ((const float4*)qkv_w)[v]);
    } else if (v < CV_S1) {
        int e = v - CV_S0;
        store_bf4(w_proj + (size_t)e * 4, ((const float4*)proj_w)[e]);
    } else if (v < CV_S2) {
        size_t e = (size_t)(v - CV_S1) * 4;
        int row = (int)(e / DD);              // [0, 2*MLP_P)
        int c = (int)(e % DD);
        int l = row / MLP_P, lr = row % MLP_P;
        float4 f = z4;
        if (lr < MLP_R)
            f = *(const float4*)(fc1_w + ((size_t)l * MLP_R + lr) * DD + c);
        store_bf4(w_fc1 + e, f);
    } else if (v < CV_S3) {
        size_t e = (size_t)(v - CV_S2) * 4;
        int row = (int)(e / MLP_P);           // [0, 2*DD)
        int c = (int)(e % MLP_P);
        float4 f = z4;
        if (c < MLP_R)
            f = *(const float4*)(fc2_w + (size_t)row * MLP_R + c);
        store_bf4(w_fc2 + e, f);
    } else if (v < CV_S4) {
        size_t e = (size_t)(v - CV_S3) * 4;
        int row = (int)(e / KP);
        int c = (int)(e % KP);
        float4 f = z4;
        if (c < 588)
            f = *(const float4*)(patch_w + (size_t)row * 588 + c);
        store_bf4(w_pat + e, f);
    } else {
        size_t e = (size_t)(v - CV_S4) * 4;
        int l = (int)(e / MLP_P);
        int c = (int)(e % MLP_P);
        float4 f = z4;
        if (c < MLP_R)
            f = *(const float4*)(fc1_b + (size_t)l * MLP_R + c);
        *(float4*)(fc1b_p + e) = f;
    }
}

// ---------------------------------------------------------------------------
// Workspace layout (bytes)
// ---------------------------------------------------------------------------
constexpr size_t OFF_X      = 0;                                  // f32 [NT][DD]
constexpr size_t OFF_HBF    = OFF_X      + (size_t)NT * DD * 4;   // bf16 [NT][DD]
constexpr size_t OFF_TMP    = OFF_HBF    + (size_t)NT * DD * 2;   // bf16 max(NT*MLP_P, NT*NT)
constexpr size_t OFF_QKV    = OFF_TMP    + (size_t)NT * MLP_P * 2;// bf16 [NT][D3]
constexpr size_t OFF_VT     = OFF_QKV    + (size_t)NT * D3 * 2;   // bf16 [DD][NT]
constexpr size_t OFF_IM     = OFF_VT     + (size_t)DD * NT * 2;   // bf16 [NT][KP]
constexpr size_t OFF_WQKV   = OFF_IM     + (size_t)NT * KP * 2;   // bf16 [2][D3][DD]
constexpr size_t OFF_WPROJ  = OFF_WQKV   + (size_t)2 * D3 * DD * 2;
constexpr size_t OFF_WFC1   = OFF_WPROJ  + (size_t)2 * DD * DD * 2;   // [2][MLP_P][DD]
constexpr size_t OFF_WFC2   = OFF_WFC1   + (size_t)2 * MLP_P * DD * 2;// [2][DD][MLP_P]
constexpr size_t OFF_WPATCH = OFF_WFC2   + (size_t)2 * DD * MLP_P * 2;// [DD][KP]
constexpr size_t OFF_FC1B   = OFF_WPATCH + (size_t)DD * KP * 2;       // f32 [2][MLP_P]

extern "C" void kernel_launch(void* const* d_in, const int* in_sizes, int n_in,
                              void* d_out, int out_size, void* d_ws, size_t ws_size,
                              hipStream_t stream)
{
    const float* img     = (const float*)d_in[0];
    const float* patch_w = (const float*)d_in[1];
    const float* patch_b = (const float*)d_in[2];
    const float* pos     = (const float*)d_in[3];
    const float* ln1_w   = (const float*)d_in[4];
    const float* ln1_b   = (const float*)d_in[5];
    const float* qkv_w   = (const float*)d_in[6];
    const float* qkv_b   = (const float*)d_in[7];
    const float* proj_w  = (const float*)d_in[8];
    const float* proj_b  = (const float*)d_in[9];
    const float* ln2_w   = (const float*)d_in[10];
    const float* ln2_b   = (const float*)d_in[11];
    const float* fc1_w   = (const float*)d_in[12];
    const float* fc1_b   = (const float*)d_in[13];
    const float* fc2_w   = (const float*)d_in[14];
    const float* fc2_b   = (const float*)d_in[15];
    const float* post_w  = (const float*)d_in[16];
    const float* post_b  = (const float*)d_in[17];

    char* ws = (char*)d_ws;
    float* x      = (float*)(ws + OFF_X);
    u16*  h_bf    = (u16*)(ws + OFF_HBF);
    u16*  tmp_bf  = (u16*)(ws + OFF_TMP);
    u16*  qkv_bf  = (u16*)(ws + OFF_QKV);
    u16*  vt      = (u16*)(ws + OFF_VT);
    u16*  a_im    = (u16*)(ws + OFF_IM);
    u16*  w_qkv   = (u16*)(ws + OFF_WQKV);
    u16*  w_proj  = (u16*)(ws + OFF_WPROJ);
    u16*  w_fc1   = (u16*)(ws + OFF_WFC1);
    u16*  w_fc2   = (u16*)(ws + OFF_WFC2);
    u16*  w_pat   = (u16*)(ws + OFF_WPATCH);
    float* fc1b_p = (float*)(ws + OFF_FC1B);

    // ---- fused weight/bias conversion (1 dispatch) + im2col ----
    convert_all<<<CV_BLOCKS, 256, 0, stream>>>(
        qkv_w, proj_w, fc1_w, fc2_w, patch_w, fc1_b,
        w_qkv, w_proj, w_fc1, w_fc2, w_pat, fc1b_p);
    im2col_kernel<<<dim3(3, NT), 256, 0, stream>>>(img, a_im);

    // ---- patch embed: x = im2col * patch_w^T + patch_b + pos (fused T) ----
    gemm_bt<4, 64><<<dim3(9, 64), 256, 0, stream>>>(
        a_im, KP, w_pat, KP, KP, patch_b, pos, x, nullptr, DD, nullptr);

    for (int l = 0; l < 2; ++l) {
        // LN1 -> bf16
        ln_kernel<0><<<NT, 384, 0, stream>>>(x, ln1_w + l * DD, ln1_b + l * DD, h_bf);
        // QKV = h * Wqkv^T + b   (+ fused V-transpose into vt)
        gemm_bt<1, 128><<<dim3(27, 32), 256, 0, stream>>>(
            h_bf, DD, w_qkv + (size_t)l * D3 * DD, DD, DD,
            qkv_b + (size_t)l * D3, nullptr, nullptr, qkv_bf, D3, vt);
        // scores = Q K^T (bf16 out, scaled inside softmax)
        gemm_bt<0, 128><<<dim3(32, 32), 256, 0, stream>>>(
            qkv_bf, D3, qkv_bf + DD, D3, DD,
            nullptr, nullptr, nullptr, tmp_bf, NT, nullptr);
        // softmax rows (in place)
        softmax_kernel<<<NT, 256, 0, stream>>>(tmp_bf);
        // attn_out = P * V   (B = V^T)
        gemm_bt<0, 64><<<dim3(9, 64), 256, 0, stream>>>(
            tmp_bf, NT, vt, NT, NT, nullptr, nullptr, nullptr, h_bf, DD, nullptr);
        // x += attn_out * Wproj^T + b
        gemm_bt<3, 64><<<dim3(9, 64), 256, 0, stream>>>(
            h_bf, DD, w_proj + (size_t)l * DD * DD, DD, DD,
            proj_b + (size_t)l * DD, x, x, nullptr, DD, nullptr);
        // LN2 -> bf16
        ln_kernel<0><<<NT, 384, 0, stream>>>(x, ln2_w + l * DD, ln2_b + l * DD, h_bf);
        // h2 = gelu(h * Wfc1^T + b)   (MLP padded 4304 -> 4352, pad cols = 0)
        gemm_bt<2, 128><<<dim3(34, 32), 256, 0, stream>>>(
            h_bf, DD, w_fc1 + (size_t)l * MLP_P * DD, DD, DD,
            fc1b_p + (size_t)l * MLP_P, nullptr, nullptr, tmp_bf, MLP_P, nullptr);
        // x += h2 * Wfc2^T + b
        gemm_bt<3, 64><<<dim3(9, 64), 256, 0, stream>>>(
            tmp_bf, MLP_P, w_fc2 + (size_t)l * DD * MLP_P, MLP_P, MLP_P,
            fc2_b + (size_t)l * DD, x, x, nullptr, DD, nullptr);
    }
    // final LN -> f32 d_out
    ln_kernel<1><<<NT, 384, 0, stream>>>(x, post_w, post_b, d_out);
}

// Round 6
// 957.260 us; speedup vs baseline: 1.2104x; 1.0486x over previous
//
#include <hip/hip_runtime.h>

#define NT 4096
#define DD 1152
#define D3 3456
#define MLP_R 4304
#define MLP_P 4352
#define KP 640

typedef unsigned short u16;
typedef short v8s __attribute__((ext_vector_type(8)));
typedef float v4f __attribute__((ext_vector_type(4)));

__device__ __forceinline__ u16 f2b(float f) {
    unsigned int u = __builtin_bit_cast(unsigned int, f);
    u += 0x7fffu + ((u >> 16) & 1u);          // round-to-nearest-even
    return (u16)(u >> 16);
}
__device__ __forceinline__ float b2f(u16 s) {
    unsigned int u = ((unsigned int)s) << 16;
    return __builtin_bit_cast(float, u);
}

__device__ __forceinline__ void async16(const void* g, void* l) {
    __builtin_amdgcn_global_load_lds(
        (const __attribute__((address_space(1))) void*)g,
        (__attribute__((address_space(3))) void*)l, 16, 0, 0);
}

// ---------------------------------------------------------------------------
// GEMM: C[m][n] = sum_k A[m][k] * B[n][k]   (B transposed, K contiguous)
// Round-3 core (proven). 1-D grid of NX*NY blocks, XCD-compact remap:
// xcd = b&7 owns m-tiles [xcd*MY, (xcd+1)*MY), MY = NY/8 — shrinks each
// per-XCD L2 working set from (all A + all B) to (A-stripe + B).
// EPI: 0 = bf16 out; 1 = bf16(acc+bias), + transposed V store when vt!=null;
//      2 = bf16(gelu(acc+bias)); 3 = f32 out = aux + acc + bias;
//      4 = f32 out = acc + bias[n] + pos[n][m]  (aux = pos, [D][NT] layout)
// ---------------------------------------------------------------------------
template<int EPI, int MT>
__global__ __launch_bounds__(256)
void gemm_bt(const u16* __restrict__ A, int lda,
             const u16* __restrict__ B, int ldb, int Kdim,
             const float* __restrict__ bias, const float* __restrict__ aux,
             float* __restrict__ outf, u16* __restrict__ outb, int ldc,
             u16* __restrict__ vt, int NX)
{
    constexpr int JT = (MT == 128) ? 4 : 2;   // 16-col j-tiles per wave
    constexpr int AR = MT * 8 / 256;          // A staging rounds (4 or 2)

    __shared__ union SM {
        struct { u16 a[MT * 64]; u16 b[128 * 64]; } st;
        float sc[4][64][17];
    } sm;

    // XCD-compact block remap (NY must be divisible by 8)
    const int b    = blockIdx.x;
    const int MY   = (gridDim.x >> 3) / NX;   // m-tiles per XCD
    const int q    = b >> 3;
    const int m0   = ((b & 7) * MY + q % MY) * MT;
    const int n0   = (q / MY) * 128;

    const int tid  = threadIdx.x;
    const int lane = tid & 63;
    const int wave = tid >> 6;
    const int wm   = (MT == 128) ? (wave & 1) * 64 : 0;
    const int wn   = (MT == 128) ? (wave >> 1) * 64 : wave * 32;
    const int fr   = lane & 15;          // fragment row within 16
    const int kqh  = lane >> 4;          // k-quarter 0..3
    const int swz  = fr & 7;             // xor key (row&7 == fr&7 for all tiles)

    v4f acc[4][JT];
    const v4f vzero = {0.f, 0.f, 0.f, 0.f};
#pragma unroll
    for (int i = 0; i < 4; ++i)
#pragma unroll
        for (int j = 0; j < JT; ++j) acc[i][j] = vzero;

    u16* As = sm.st.a;
    u16* Bs = sm.st.b;

    for (int kt = 0; kt < Kdim; kt += 64) {
#pragma unroll
        for (int r = 0; r < AR; ++r) {
            int c = r * 256 + tid;
            int row = c >> 3;
            int kc = (c & 7) ^ (row & 7);
            async16(A + (size_t)(m0 + row) * lda + kt + kc * 8, As + c * 8);
        }
#pragma unroll
        for (int r = 0; r < 4; ++r) {
            int c = r * 256 + tid;
            int row = c >> 3;
            int kc = (c & 7) ^ (row & 7);
            async16(B + (size_t)(n0 + row) * ldb + kt + kc * 8, Bs + c * 8);
        }
        __syncthreads();
#pragma unroll
        for (int ks = 0; ks < 2; ++ks) {
            const int kq = ks * 4 + kqh;
            const int kp = (kq ^ swz) * 8;
            v8s af[4], bf[JT];
#pragma unroll
            for (int i = 0; i < 4; ++i)
                af[i] = *(const v8s*)(As + (wm + i * 16 + fr) * 64 + kp);
#pragma unroll
            for (int j = 0; j < JT; ++j)
                bf[j] = *(const v8s*)(Bs + (wn + j * 16 + fr) * 64 + kp);
#pragma unroll
            for (int i = 0; i < 4; ++i)
#pragma unroll
                for (int j = 0; j < JT; ++j)
                    acc[i][j] = __builtin_amdgcn_mfma_f32_16x16x32_bf16(
                        af[i], bf[j], acc[i][j], 0, 0, 0);
        }
        __syncthreads();
    }

    // ---- epilogue via LDS transpose ----
    // acc C/D layout: col = lane&15, row = (lane>>4)*4 + reg
    const int cn = lane & 15;
    const int cm = (lane >> 4) * 4;
    float (*S)[17] = sm.sc[wave];
    const int gm = m0 + wm + lane;       // this thread's output row (store phase)
#pragma unroll
    for (int jp = 0; jp < JT; ++jp) {
        __syncthreads();
#pragma unroll
        for (int i = 0; i < 4; ++i)
#pragma unroll
            for (int r = 0; r < 4; ++r)
                S[i * 16 + cm + r][cn] = acc[i][jp][r];
        __syncthreads();
        const int gn0 = n0 + wn + jp * 16;
        float v[16];
#pragma unroll
        for (int c = 0; c < 16; ++c) v[c] = S[lane][c];
        if constexpr (EPI <= 2) {
            union { u16 us[16]; uint4 q4[2]; } o;
#pragma unroll
            for (int c = 0; c < 16; ++c) {
                float t = v[c];
                if constexpr (EPI >= 1) t += bias[gn0 + c];
                if constexpr (EPI == 2) {
                    // tanh-form gelu: t * sigmoid(2u), u = 0.79788t(1+0.044715t^2)
                    float u = t * (0.7978845608028654f + 0.03567740814183026f * t * t);
                    t = t / (1.0f + __expf(-2.0f * u));
                }
                o.us[c] = f2b(t);
            }
            uint4* dst = (uint4*)(outb + (size_t)gm * ldc + gn0);
            dst[0] = o.q4[0];
            dst[1] = o.q4[1];
            if constexpr (EPI == 1) {
                // fused V-transpose: V section of qkv -> vt [DD][NT]
                if (vt != nullptr && gn0 >= 2304) {
#pragma unroll
                    for (int c = 0; c < 16; ++c)
                        vt[(size_t)(gn0 + c - 2304) * NT + gm] = o.us[c];
                }
            }
        } else if constexpr (EPI == 3) {
            float* dst = outf + (size_t)gm * ldc + gn0;
            const float* ax = aux + (size_t)gm * ldc + gn0;
#pragma unroll
            for (int c = 0; c < 4; ++c) {
                float4 a4 = ((const float4*)ax)[c];
                float4 r4;
                r4.x = a4.x + v[4 * c + 0] + bias[gn0 + 4 * c + 0];
                r4.y = a4.y + v[4 * c + 1] + bias[gn0 + 4 * c + 1];
                r4.z = a4.z + v[4 * c + 2] + bias[gn0 + 4 * c + 2];
                r4.w = a4.w + v[4 * c + 3] + bias[gn0 + 4 * c + 3];
                ((float4*)dst)[c] = r4;
            }
        } else {
            // EPI 4: patch embed. aux = pos in [D][NT] layout, read transposed
            // (coalesced across lanes since gm is lane-consecutive).
            float* dst = outf + (size_t)gm * ldc + gn0;
#pragma unroll
            for (int c = 0; c < 4; ++c) {
                float4 r4;
                r4.x = v[4 * c + 0] + bias[gn0 + 4 * c + 0] + aux[(size_t)(gn0 + 4 * c + 0) * NT + gm];
                r4.y = v[4 * c + 1] + bias[gn0 + 4 * c + 1] + aux[(size_t)(gn0 + 4 * c + 1) * NT + gm];
                r4.z = v[4 * c + 2] + bias[gn0 + 4 * c + 2] + aux[(size_t)(gn0 + 4 * c + 2) * NT + gm];
                r4.w = v[4 * c + 3] + bias[gn0 + 4 * c + 3] + aux[(size_t)(gn0 + 4 * c + 3) * NT + gm];
                ((float4*)dst)[c] = r4;
            }
        }
    }
}

// ---------------------------------------------------------------------------
// LayerNorm over D=1152. 384 threads, 3 elems each. OUTF=1 -> f32, else bf16.
// ---------------------------------------------------------------------------
template<int OUTF>
__global__ __launch_bounds__(384)
void ln_kernel(const float* __restrict__ x, const float* __restrict__ w,
               const float* __restrict__ b, void* __restrict__ out)
{
    const int n = blockIdx.x;
    const int t = threadIdx.x;
    const float* row = x + (size_t)n * DD;
    float v0 = row[t], v1 = row[t + 384], v2 = row[t + 768];
    float s  = v0 + v1 + v2;
    float ss = v0 * v0 + v1 * v1 + v2 * v2;
#pragma unroll
    for (int o = 32; o > 0; o >>= 1) {
        s  += __shfl_down(s, o);
        ss += __shfl_down(ss, o);
    }
    __shared__ float ps[6], pss[6], mh[2];
    if ((t & 63) == 0) { ps[t >> 6] = s; pss[t >> 6] = ss; }
    __syncthreads();
    if (t == 0) {
        float S = 0.f, SS = 0.f;
        for (int i = 0; i < 6; ++i) { S += ps[i]; SS += pss[i]; }
        float m = S / (float)DD;
        float var = SS / (float)DD - m * m;
        mh[0] = m;
        mh[1] = rsqrtf(var + 1e-6f);
    }
    __syncthreads();
    const float m = mh[0], rs = mh[1];
#pragma unroll
    for (int j = 0; j < 3; ++j) {
        int c = t + j * 384;
        float y = (row[c] - m) * rs * w[c] + b[c];
        if constexpr (OUTF) ((float*)out)[(size_t)n * DD + c] = y;
        else                ((u16*)out)[(size_t)n * DD + c]   = f2b(y);
    }
}

// ---------------------------------------------------------------------------
// Softmax over rows of bf16 scores [NT x NT], in place, with scale.
// ---------------------------------------------------------------------------
__global__ __launch_bounds__(256)
void softmax_kernel(u16* __restrict__ s)
{
    const float SC = 0.029462782549439484f;  // 1/sqrt(1152)
    const int row = blockIdx.x;
    const int t = threadIdx.x;
    u16* p = s + (size_t)row * NT + t * 16;
    uint4 u0 = *(const uint4*)p;
    uint4 u1 = *(const uint4*)(p + 8);
    float v[16];
    unsigned int w[8] = {u0.x, u0.y, u0.z, u0.w, u1.x, u1.y, u1.z, u1.w};
#pragma unroll
    for (int i = 0; i < 8; ++i) {
        v[2 * i]     = b2f((u16)(w[i] & 0xffffu)) * SC;
        v[2 * i + 1] = b2f((u16)(w[i] >> 16)) * SC;
    }
    float mx = -1e30f;
#pragma unroll
    for (int i = 0; i < 16; ++i) mx = fmaxf(mx, v[i]);
#pragma unroll
    for (int o = 32; o > 0; o >>= 1) mx = fmaxf(mx, __shfl_down(mx, o));
    __shared__ float red[4];
    __shared__ float bc;
    if ((t & 63) == 0) red[t >> 6] = mx;
    __syncthreads();
    if (t == 0) bc = fmaxf(fmaxf(red[0], red[1]), fmaxf(red[2], red[3]));
    __syncthreads();
    const float M = bc;
    float sum = 0.f;
#pragma unroll
    for (int i = 0; i < 16; ++i) { v[i] = __expf(v[i] - M); sum += v[i]; }
#pragma unroll
    for (int o = 32; o > 0; o >>= 1) sum += __shfl_down(sum, o);
    __syncthreads();
    if ((t & 63) == 0) red[t >> 6] = sum;
    __syncthreads();
    if (t == 0) bc = red[0] + red[1] + red[2] + red[3];
    __syncthreads();
    const float inv = 1.0f / bc;
    union { u16 us[8]; uint4 u4; } o0, o1;
#pragma unroll
    for (int i = 0; i < 8; ++i) o0.us[i] = f2b(v[i] * inv);
#pragma unroll
    for (int i = 0; i < 8; ++i) o1.us[i] = f2b(v[8 + i] * inv);
    *(uint4*)p = o0.u4;
    *(uint4*)(p + 8) = o1.u4;
}

// ---------------------------------------------------------------------------
// im2col: img [3][896][896] -> a [NT][KP] bf16 (k = cin*196+py*14+px, pad->0)
// ---------------------------------------------------------------------------
__global__ __launch_bounds__(256)
void im2col_kernel(const float* __restrict__ img, u16* __restrict__ a)
{
    const int k = blockIdx.x * 256 + threadIdx.x;
    const int n = blockIdx.y;
    if (k >= KP) return;
    float v = 0.f;
    if (k < 588) {
        int cin = k / 196;
        int rr = k - cin * 196;
        int py = rr / 14;
        int px = rr - py * 14;
        int gy = (n >> 6) * 14 + py;
        int gx = (n & 63) * 14 + px;
        v = img[(size_t)cin * 896 * 896 + (size_t)gy * 896 + gx];
    }
    a[(size_t)n * KP + k] = f2b(v);
}

// ---------------------------------------------------------------------------
// One fused, float4-vectorized weight conversion/pad kernel.
// ---------------------------------------------------------------------------
constexpr int CV_S0 = 2 * D3 * DD / 4;
constexpr int CV_S1 = CV_S0 + 2 * DD * DD / 4;
constexpr int CV_S2 = CV_S1 + 2 * MLP_P * DD / 4;
constexpr int CV_S3 = CV_S2 + 2 * DD * MLP_P / 4;
constexpr int CV_S4 = CV_S3 + DD * KP / 4;
constexpr int CV_S5 = CV_S4 + 2 * MLP_P / 4;
constexpr int CV_BLOCKS = (CV_S5 + 255) / 256;

__device__ __forceinline__ void store_bf4(u16* p, float4 f) {
    union { u16 s[4]; uint2 d; } o;
    o.s[0] = f2b(f.x); o.s[1] = f2b(f.y); o.s[2] = f2b(f.z); o.s[3] = f2b(f.w);
    *(uint2*)p = o.d;
}

__global__ __launch_bounds__(256)
void convert_all(const float* __restrict__ qkv_w, const float* __restrict__ proj_w,
                 const float* __restrict__ fc1_w, const float* __restrict__ fc2_w,
                 const float* __restrict__ patch_w, const float* __restrict__ fc1_b,
                 u16* __restrict__ w_qkv, u16* __restrict__ w_proj,
                 u16* __restrict__ w_fc1, u16* __restrict__ w_fc2,
                 u16* __restrict__ w_pat, float* __restrict__ fc1b_p)
{
    int v = blockIdx.x * 256 + threadIdx.x;
    if (v >= CV_S5) return;
    const float4 z4 = {0.f, 0.f, 0.f, 0.f};
    if (v < CV_S0) {
        store_bf4(w_qkv + (size_t)v * 4, ((const float4*)qkv_w)[v]);
    } else if (v < CV_S1) {
        int e = v - CV_S0;
        store_bf4(w_proj + (size_t)e * 4, ((const float4*)proj_w)[e]);
    } else if (v < CV_S2) {
        size_t e = (size_t)(v - CV_S1) * 4;
        int row = (int)(e / DD);
        int c = (int)(e % DD);
        int l = row / MLP_P, lr = row % MLP_P;
        float4 f = z4;
        if (lr < MLP_R)
            f = *(const float4*)(fc1_w + ((size_t)l * MLP_R + lr) * DD + c);
        store_bf4(w_fc1 + e, f);
    } else if (v < CV_S3) {
        size_t e = (size_t)(v - CV_S2) * 4;
        int row = (int)(e / MLP_P);
        int c = (int)(e % MLP_P);
        float4 f = z4;
        if (c < MLP_R)
            f = *(const float4*)(fc2_w + (size_t)row * MLP_R + c);
        store_bf4(w_fc2 + e, f);
    } else if (v < CV_S4) {
        size_t e = (size_t)(v - CV_S3) * 4;
        int row = (int)(e / KP);
        int c = (int)(e % KP);
        float4 f = z4;
        if (c < 588)
            f = *(const float4*)(patch_w + (size_t)row * 588 + c);
        store_bf4(w_pat + e, f);
    } else {
        size_t e = (size_t)(v - CV_S4) * 4;
        int l = (int)(e / MLP_P);
        int c = (int)(e % MLP_P);
        float4 f = z4;
        if (c < MLP_R)
            f = *(const float4*)(fc1_b + (size_t)l * MLP_R + c);
        *(float4*)(fc1b_p + e) = f;
    }
}

// ---------------------------------------------------------------------------
// Workspace layout (bytes)
// ---------------------------------------------------------------------------
constexpr size_t OFF_X      = 0;                                  // f32 [NT][DD]
constexpr size_t OFF_HBF    = OFF_X      + (size_t)NT * DD * 4;   // bf16 [NT][DD]
constexpr size_t OFF_TMP    = OFF_HBF    + (size_t)NT * DD * 2;   // bf16 max(NT*MLP_P, NT*NT)
constexpr size_t OFF_QKV    = OFF_TMP    + (size_t)NT * MLP_P * 2;// bf16 [NT][D3]
constexpr size_t OFF_VT     = OFF_QKV    + (size_t)NT * D3 * 2;   // bf16 [DD][NT]
constexpr size_t OFF_IM     = OFF_VT     + (size_t)DD * NT * 2;   // bf16 [NT][KP]
constexpr size_t OFF_WQKV   = OFF_IM     + (size_t)NT * KP * 2;   // bf16 [2][D3][DD]
constexpr size_t OFF_WPROJ  = OFF_WQKV   + (size_t)2 * D3 * DD * 2;
constexpr size_t OFF_WFC1   = OFF_WPROJ  + (size_t)2 * DD * DD * 2;   // [2][MLP_P][DD]
constexpr size_t OFF_WFC2   = OFF_WFC1   + (size_t)2 * MLP_P * DD * 2;// [2][DD][MLP_P]
constexpr size_t OFF_WPATCH = OFF_WFC2   + (size_t)2 * DD * MLP_P * 2;// [DD][KP]
constexpr size_t OFF_FC1B   = OFF_WPATCH + (size_t)DD * KP * 2;       // f32 [2][MLP_P]

extern "C" void kernel_launch(void* const* d_in, const int* in_sizes, int n_in,
                              void* d_out, int out_size, void* d_ws, size_t ws_size,
                              hipStream_t stream)
{
    const float* img     = (const float*)d_in[0];
    const float* patch_w = (const float*)d_in[1];
    const float* patch_b = (const float*)d_in[2];
    const float* pos     = (const float*)d_in[3];
    const float* ln1_w   = (const float*)d_in[4];
    const float* ln1_b   = (const float*)d_in[5];
    const float* qkv_w   = (const float*)d_in[6];
    const float* qkv_b   = (const float*)d_in[7];
    const float* proj_w  = (const float*)d_in[8];
    const float* proj_b  = (const float*)d_in[9];
    const float* ln2_w   = (const float*)d_in[10];
    const float* ln2_b   = (const float*)d_in[11];
    const float* fc1_w   = (const float*)d_in[12];
    const float* fc1_b   = (const float*)d_in[13];
    const float* fc2_w   = (const float*)d_in[14];
    const float* fc2_b   = (const float*)d_in[15];
    const float* post_w  = (const float*)d_in[16];
    const float* post_b  = (const float*)d_in[17];

    char* ws = (char*)d_ws;
    float* x      = (float*)(ws + OFF_X);
    u16*  h_bf    = (u16*)(ws + OFF_HBF);
    u16*  tmp_bf  = (u16*)(ws + OFF_TMP);
    u16*  qkv_bf  = (u16*)(ws + OFF_QKV);
    u16*  vt      = (u16*)(ws + OFF_VT);
    u16*  a_im    = (u16*)(ws + OFF_IM);
    u16*  w_qkv   = (u16*)(ws + OFF_WQKV);
    u16*  w_proj  = (u16*)(ws + OFF_WPROJ);
    u16*  w_fc1   = (u16*)(ws + OFF_WFC1);
    u16*  w_fc2   = (u16*)(ws + OFF_WFC2);
    u16*  w_pat   = (u16*)(ws + OFF_WPATCH);
    float* fc1b_p = (float*)(ws + OFF_FC1B);

    // ---- fused weight/bias conversion (1 dispatch) + im2col ----
    convert_all<<<CV_BLOCKS, 256, 0, stream>>>(
        qkv_w, proj_w, fc1_w, fc2_w, patch_w, fc1_b,
        w_qkv, w_proj, w_fc1, w_fc2, w_pat, fc1b_p);
    im2col_kernel<<<dim3(3, NT), 256, 0, stream>>>(img, a_im);

    // ---- patch embed: x = im2col * patch_w^T + patch_b + pos (fused T) ----
    gemm_bt<4, 64><<<9 * 64, 256, 0, stream>>>(
        a_im, KP, w_pat, KP, KP, patch_b, pos, x, nullptr, DD, nullptr, 9);

    for (int l = 0; l < 2; ++l) {
        // LN1 -> bf16
        ln_kernel<0><<<NT, 384, 0, stream>>>(x, ln1_w + l * DD, ln1_b + l * DD, h_bf);
        // QKV = h * Wqkv^T + b   (+ fused V-transpose into vt)
        gemm_bt<1, 128><<<27 * 32, 256, 0, stream>>>(
            h_bf, DD, w_qkv + (size_t)l * D3 * DD, DD, DD,
            qkv_b + (size_t)l * D3, nullptr, nullptr, qkv_bf, D3, vt, 27);
        // scores = Q K^T (bf16 out, scaled inside softmax)
        gemm_bt<0, 128><<<32 * 32, 256, 0, stream>>>(
            qkv_bf, D3, qkv_bf + DD, D3, DD,
            nullptr, nullptr, nullptr, tmp_bf, NT, nullptr, 32);
        // softmax rows (in place)
        softmax_kernel<<<NT, 256, 0, stream>>>(tmp_bf);
        // attn_out = P * V   (B = V^T)
        gemm_bt<0, 64><<<9 * 64, 256, 0, stream>>>(
            tmp_bf, NT, vt, NT, NT, nullptr, nullptr, nullptr, h_bf, DD, nullptr, 9);
        // x += attn_out * Wproj^T + b
        gemm_bt<3, 64><<<9 * 64, 256, 0, stream>>>(
            h_bf, DD, w_proj + (size_t)l * DD * DD, DD, DD,
            proj_b + (size_t)l * DD, x, x, nullptr, DD, nullptr, 9);
        // LN2 -> bf16
        ln_kernel<0><<<NT, 384, 0, stream>>>(x, ln2_w + l * DD, ln2_b + l * DD, h_bf);
        // h2 = gelu(h * Wfc1^T + b)   (MLP padded 4304 -> 4352, pad cols = 0)
        gemm_bt<2, 128><<<34 * 32, 256, 0, stream>>>(
            h_bf, DD, w_fc1 + (size_t)l * MLP_P * DD, DD, DD,
            fc1b_p + (size_t)l * MLP_P, nullptr, nullptr, tmp_bf, MLP_P, nullptr, 34);
        // x += h2 * Wfc2^T + b
        gemm_bt<3, 64><<<9 * 64, 256, 0, stream>>>(
            tmp_bf, MLP_P, w_fc2 + (size_t)l * DD * MLP_P, MLP_P, MLP_P,
            fc2_b + (size_t)l * DD, x, x, nullptr, DD, nullptr, 9);
    }
    // final LN -> f32 d_out
    ln_kernel<1><<<NT, 384, 0, stream>>>(x, post_w, post_b, d_out);
}